// Round 1
// 800.852 us; speedup vs baseline: 2.3341x; 2.3341x over previous
//
#include <hip/hip_runtime.h>
#include <math.h>

#define B_    16
#define N_    128
#define R_    16256
#define OBJD  64
#define RELD  32
#define EFFD  100
#define HID   150
#define MT    64             // relations per block
#define NTILE (R_ / MT)      // 254

typedef __bf16 bf16x8 __attribute__((ext_vector_type(8)));
typedef float  f32x4  __attribute__((ext_vector_type(4)));
typedef unsigned int  uint4v __attribute__((ext_vector_type(4)));
typedef unsigned short u16;
typedef unsigned long long u64;

#define MFMA(a,b,c) (c) = __builtin_amdgcn_mfma_f32_16x16x32_bf16((a), (b), (c), 0, 0, 0)

// ---------------- ws layout ----------------
// [float EF | u16 region: A1H A1L W2H W2L W3H W3L W4H W4L]
#define EF_FLOATS (B_*N_*EFFD)       // 204800
#define A1_ELEMS  (B_*160*288)       // 737280
#define W2_ELEMS  (160*160)          // 25600
#define W4_ELEMS  (128*160)          // 20480
#define U_A1H 0
#define U_A1L (U_A1H + A1_ELEMS)
#define U_W2H (U_A1L + A1_ELEMS)
#define U_W2L (U_W2H + W2_ELEMS)
#define U_W3H (U_W2L + W2_ELEMS)
#define U_W3L (U_W3H + W2_ELEMS)
#define U_W4H (U_W3L + W2_ELEMS)
#define U_W4L (U_W4H + W4_ELEMS)

// ---- bf16 split helpers: x = hi + lo, both RNE bf16 ----
__device__ __forceinline__ u16 bfh(float x){
    unsigned u = __float_as_uint(x);
    return (u16)((u + 0x7FFFu + ((u >> 16) & 1u)) >> 16);
}
__device__ __forceinline__ float bff(u16 h){ return __uint_as_float(((unsigned)h) << 16); }
__device__ __forceinline__ void split2(float x, u16 &h, u16 &l){
    h = bfh(x);
    l = bfh(x - bff(h));
}
__device__ __forceinline__ u64 pack4(const u16 h[4]){
    return (u64)((unsigned)h[0] | ((unsigned)h[1] << 16))
         | ((u64)((unsigned)h[2] | ((unsigned)h[3] << 16)) << 32);
}

// ---------------- k0a: fold objects @ rw1 -> A1[b][out 160][k 288] hi/lo bf16 ----------------
// k<128: sender-fold row n=k ; 128..255: receiver-fold ; 256..287: rw1 rel rows.
// LDS granule swizzle pre-baked: within each 32-k chunk, gran g stored at g^(out&3).
__global__ __launch_bounds__(128) void k0a(const float* __restrict__ obj,
                                           const float* __restrict__ rw1,
                                           u16* __restrict__ A1H, u16* __restrict__ A1L){
    const int j = blockIdx.x;      // out 0..159 (>=150 -> zero rows)
    const int b = blockIdx.y;
    const int n = threadIdx.x;     // 0..127
    float s = 0.f, rc = 0.f;
    if (j < HID){
        const float* o = obj + ((size_t)b*N_ + n)*OBJD;
#pragma unroll
        for (int d = 0; d < OBJD; ++d){
            const float ov = o[d];
            s  += ov * rw1[d*HID + j];
            rc += ov * rw1[(OBJD + d)*HID + j];
        }
    }
    const size_t base = ((size_t)b*160 + j)*288;
    const int pos = (n & ~31) + (((((n >> 3) & 3) ^ (j & 3))) << 3) + (n & 7);
    u16 h, l;
    split2(s, h, l);  A1H[base + pos] = h;        A1L[base + pos] = l;
    split2(rc, h, l); A1H[base + 128 + pos] = h;  A1L[base + 128 + pos] = l;
    if (n < RELD){
        const float v = (j < HID) ? rw1[(2*OBJD + n)*HID + j] : 0.f;
        const int p2 = 256 + ((((n >> 3) & 3) ^ (j & 3)) << 3) + (n & 7);
        split2(v, h, l); A1H[base + p2] = h; A1L[base + p2] = l;
    }
}

// ---------------- k0b: transpose+split rw2/rw3/rw4 (swizzle pre-baked) ----------------
__global__ __launch_bounds__(160) void k0b(const float* __restrict__ rw2,
                                           const float* __restrict__ rw3,
                                           const float* __restrict__ rw4,
                                           u16* W2H, u16* W2L, u16* W3H, u16* W3L,
                                           u16* W4H, u16* W4L){
    const int out = blockIdx.x;    // 0..159
    const int m   = blockIdx.y;    // 0:rw2 1:rw3 2:rw4
    const int k   = threadIdx.x;   // 0..159
    const int pos = (k & ~31) + ((((k >> 3) & 3) ^ (out & 3)) << 3) + (k & 7);
    u16 h, l;
    if (m == 2){
        if (out >= 128) return;
        const float v = (out < EFFD && k < HID) ? rw4[k*EFFD + out] : 0.f;
        split2(v, h, l);
        W4H[out*160 + pos] = h; W4L[out*160 + pos] = l;
    } else {
        const float* W = (m == 0) ? rw2 : rw3;
        u16* DH = (m == 0) ? W2H : W3H;
        u16* DL = (m == 0) ? W2L : W3L;
        const float v = (out < HID && k < HID) ? W[k*HID + out] : 0.f;
        split2(v, h, l);
        DH[out*160 + pos] = h; DL[out*160 + pos] = l;
    }
}

// ---------------- k1: MFMA split-bf16 GEMM chain + fused MFMA scatter ----------------
// LDS regions (bytes):
#define ACT_H 0        // [64 rel][20 gran] bf16 hi   (rows 160 k)
#define ACT_L 20480
#define WA_H  40960    // weight chunk [<=160 rows][4 gran]
#define WA_L  51200
#define BS_H  61440    // G1 B chunk [64 rel][4 gran]
#define BS_L  65536
// E-phase overlay:
#define RRE_H 0        // [128 n][10 gran] (8 real)
#define RRE_L 20480
#define EFF_H 40960    // [128 e][10 gran] (8 real)
#define EFF_L 61440
#define SMEM_BYTES 81920

__global__ __launch_bounds__(256, 2) void k1(
    const float* __restrict__ SR, const float* __restrict__ RR, const float* __restrict__ REL,
    const float* __restrict__ rb1, const float* __restrict__ rb2,
    const float* __restrict__ rb3, const float* __restrict__ rb4,
    const u16* __restrict__ UA, float* __restrict__ EF){

    __shared__ __align__(16) unsigned char smem[SMEM_BYTES];

    const int t    = threadIdx.x;
    const int wid  = t >> 6;        // wave 0..3
    const int lane = t & 63;
    const int lr   = lane & 15;     // row/col within 16-block
    const int lg   = lane >> 4;     // k-granule 0..3
    const int wr   = wid >> 1;      // out/rel/n half
    const int wc   = wid & 1;       // rel/e half
    const int b    = blockIdx.y;
    const int r0   = blockIdx.x * MT;

    const u16* A1Hb = UA + U_A1H + (size_t)b*160*288;
    const u16* A1Lb = UA + U_A1L + (size_t)b*160*288;

    u64 wh[5], wl[5];     // weight chunk staging regs
    float bsv[8];         // G1 B staging regs

    auto wload = [&](const u16* GH, const u16* GL, int KW, int pieces, int c){
#pragma unroll
        for (int q = 0; q < 5; ++q){
            const int p = t + 256*q;
            if (p < pieces){
                const size_t off = (size_t)(p >> 3)*KW + c*32 + (p & 7)*4;
                wh[q] = *(const u64*)(GH + off);
                wl[q] = *(const u64*)(GL + off);
            }
        }
    };
    auto wwrite = [&](int pieces){
#pragma unroll
        for (int q = 0; q < 5; ++q){
            const int p = t + 256*q;
            if (p < pieces){
                *(u64*)(smem + WA_H + p*8) = wh[q];
                *(u64*)(smem + WA_L + p*8) = wl[q];
            }
        }
    };
    // G1 B staging: SR/RR column-slices (register transpose), or REL rows
    auto bs_load_srr = [&](int c){  // chunk c: 0..3 SR, 4..7 RR; k rows = (c&3)*32 + wid*8 + q
        const float* SRC = (c < 4) ? SR : RR;
        const float* base = SRC + ((size_t)b*N_ + (c & 3)*32 + wid*8)*R_ + r0 + lane;
#pragma unroll
        for (int q = 0; q < 8; ++q) bsv[q] = base[(size_t)q * R_];
    };
    auto bs_load_rel = [&](){
        const int rel = t >> 2, gq = t & 3;
        const float* src = REL + ((size_t)b*R_ + r0 + rel)*RELD + gq*8;
#pragma unroll
        for (int q = 0; q < 8; ++q) bsv[q] = src[q];
    };
    auto bs_pack_write = [&](int rel, int gr){
        unsigned ph[4], pl[4];
#pragma unroll
        for (int i = 0; i < 4; ++i){
            u16 h0, l0, h1, l1;
            split2(bsv[2*i],   h0, l0);
            split2(bsv[2*i+1], h1, l1);
            ph[i] = (unsigned)h0 | ((unsigned)h1 << 16);
            pl[i] = (unsigned)l0 | ((unsigned)l1 << 16);
        }
        const int off = (rel*4 + (gr ^ (rel & 3))) * 16;
        uint4v H; H[0]=ph[0]; H[1]=ph[1]; H[2]=ph[2]; H[3]=ph[3];
        uint4v L; L[0]=pl[0]; L[1]=pl[1]; L[2]=pl[2]; L[3]=pl[3];
        *(uint4v*)(smem + BS_H + off) = H;
        *(uint4v*)(smem + BS_L + off) = L;
    };
    auto RD = [&](int off) -> bf16x8 {
        return __builtin_bit_cast(bf16x8, *(const uint4v*)(smem + off));
    };

    f32x4 acc[5][2];   // [out-block][rel-block], wave tile = 80 out x 32 rel

    auto epi_act = [&](){   // relu -> split -> ACT[rel][k=out]
#pragma unroll
        for (int mb = 0; mb < 5; ++mb){
            const int out0 = wr*80 + mb*16 + lg*4;
            const int g = out0 >> 3;
#pragma unroll
            for (int nb = 0; nb < 2; ++nb){
                const int rel = wc*32 + nb*16 + lr;
                const int g2 = (g & ~3) | ((g & 3) ^ (rel & 3));
                u16 h[4], l[4];
#pragma unroll
                for (int r = 0; r < 4; ++r){
                    const float v = fmaxf(acc[mb][nb][r], 0.f);
                    split2(v, h[r], l[r]);
                }
                const int ob = (rel*20 + g2)*16 + (out0 & 7)*2;
                *(u64*)(smem + ACT_H + ob) = pack4(h);
                *(u64*)(smem + ACT_L + ob) = pack4(l);
            }
        }
    };

    // ================= G1: [160 out x 64 rel], K = 288 =================
    {
#pragma unroll
        for (int mb = 0; mb < 5; ++mb){
            const int o0 = wr*80 + mb*16 + lg*4;
            f32x4 bv;
#pragma unroll
            for (int r = 0; r < 4; ++r) bv[r] = (o0 + r < HID) ? rb1[o0 + r] : 0.f;
            acc[mb][0] = bv; acc[mb][1] = bv;
        }
        wload(A1Hb, A1Lb, 288, 1280, 0);
        bs_load_srr(0);
        wwrite(1280);
        bs_pack_write(lane, wid);
        __syncthreads();
        for (int c = 0; c < 9; ++c){
            if (c < 8){
                wload(A1Hb, A1Lb, 288, 1280, c + 1);
                if (c + 1 < 8) bs_load_srr(c + 1); else bs_load_rel();
            }
            bf16x8 ah[5], al[5], bh[2], bl[2];
#pragma unroll
            for (int mb = 0; mb < 5; ++mb){
                const int row = wr*80 + mb*16 + lr;
                const int off = (row*4 + (lg ^ (row & 3))) * 16;
                ah[mb] = RD(WA_H + off); al[mb] = RD(WA_L + off);
            }
#pragma unroll
            for (int nb = 0; nb < 2; ++nb){
                const int rel = wc*32 + nb*16 + lr;
                const int off = (rel*4 + (lg ^ (rel & 3))) * 16;
                bh[nb] = RD(BS_H + off); bl[nb] = RD(BS_L + off);
            }
            __syncthreads();
#pragma unroll
            for (int mb = 0; mb < 5; ++mb)
#pragma unroll
            for (int nb = 0; nb < 2; ++nb){
                MFMA(ah[mb], bh[nb], acc[mb][nb]);
                MFMA(ah[mb], bl[nb], acc[mb][nb]);
                MFMA(al[mb], bh[nb], acc[mb][nb]);
            }
            if (c < 8){
                wwrite(1280);
                if (c + 1 < 8) bs_pack_write(lane, wid); else bs_pack_write(t >> 2, t & 3);
            }
            __syncthreads();
        }
        epi_act();
        __syncthreads();
    }

    // ================= G2, G3: [160 x 64], K = 160 (B = ACT resident) =================
    {
        const u16* WHs[2] = { UA + U_W2H, UA + U_W3H };
        const u16* WLs[2] = { UA + U_W2L, UA + U_W3L };
        const float* RBs[2] = { rb2, rb3 };
        for (int L = 0; L < 2; ++L){
#pragma unroll
            for (int mb = 0; mb < 5; ++mb){
                const int o0 = wr*80 + mb*16 + lg*4;
                f32x4 bv;
#pragma unroll
                for (int r = 0; r < 4; ++r) bv[r] = (o0 + r < HID) ? RBs[L][o0 + r] : 0.f;
                acc[mb][0] = bv; acc[mb][1] = bv;
            }
            wload(WHs[L], WLs[L], 160, 1280, 0);
            wwrite(1280);
            __syncthreads();
            for (int c = 0; c < 5; ++c){
                if (c < 4) wload(WHs[L], WLs[L], 160, 1280, c + 1);
                bf16x8 ah[5], al[5], bh[2], bl[2];
#pragma unroll
                for (int mb = 0; mb < 5; ++mb){
                    const int row = wr*80 + mb*16 + lr;
                    const int off = (row*4 + (lg ^ (row & 3))) * 16;
                    ah[mb] = RD(WA_H + off); al[mb] = RD(WA_L + off);
                }
#pragma unroll
                for (int nb = 0; nb < 2; ++nb){
                    const int rel = wc*32 + nb*16 + lr;
                    const int off = (rel*20 + c*4 + (lg ^ (rel & 3))) * 16;
                    bh[nb] = RD(ACT_H + off); bl[nb] = RD(ACT_L + off);
                }
                __syncthreads();
#pragma unroll
                for (int mb = 0; mb < 5; ++mb)
#pragma unroll
                for (int nb = 0; nb < 2; ++nb){
                    MFMA(ah[mb], bh[nb], acc[mb][nb]);
                    MFMA(ah[mb], bl[nb], acc[mb][nb]);
                    MFMA(al[mb], bh[nb], acc[mb][nb]);
                }
                if (c < 4) wwrite(1280);
                __syncthreads();
            }
            epi_act();   // in-place ACT update (reads all done before final barrier)
            __syncthreads();
        }
    }

    // ================= G4: effects, flipped: [64 rel x 128 e], K = 160 =================
    {
        f32x4 a4[2][4];
#pragma unroll
        for (int eb = 0; eb < 4; ++eb){
            const int e = wc*64 + eb*16 + lr;
            const float bvv = (e < EFFD) ? rb4[e] : 0.f;
            f32x4 v; v[0]=bvv; v[1]=bvv; v[2]=bvv; v[3]=bvv;
            a4[0][eb] = v; a4[1][eb] = v;
        }
        // prefetch RR tile for E-phase staging (consumed after the loop)
        float vrr[32];
        {
            const int n = t >> 1, half = t & 1;
            const float* src = RR + ((size_t)b*N_ + n)*R_ + r0 + half*32;
#pragma unroll
            for (int q = 0; q < 8; ++q){
                const float4 f = *(const float4*)(src + q*4);
                vrr[q*4+0] = f.x; vrr[q*4+1] = f.y; vrr[q*4+2] = f.z; vrr[q*4+3] = f.w;
            }
        }
        const u16* W4Hp = UA + U_W4H;
        const u16* W4Lp = UA + U_W4L;
        wload(W4Hp, W4Lp, 160, 1024, 0);
        wwrite(1024);
        __syncthreads();
        for (int c = 0; c < 5; ++c){
            if (c < 4) wload(W4Hp, W4Lp, 160, 1024, c + 1);
            bf16x8 ah[2], al[2], bh[4], bl[4];
#pragma unroll
            for (int rb = 0; rb < 2; ++rb){
                const int row = wr*32 + rb*16 + lr;
                const int off = (row*20 + c*4 + (lg ^ (row & 3))) * 16;
                ah[rb] = RD(ACT_H + off); al[rb] = RD(ACT_L + off);
            }
#pragma unroll
            for (int eb = 0; eb < 4; ++eb){
                const int row = wc*64 + eb*16 + lr;
                const int off = (row*4 + (lg ^ (row & 3))) * 16;
                bh[eb] = RD(WA_H + off); bl[eb] = RD(WA_L + off);
            }
            __syncthreads();
#pragma unroll
            for (int rb = 0; rb < 2; ++rb)
#pragma unroll
            for (int eb = 0; eb < 4; ++eb){
                MFMA(ah[rb], bh[eb], a4[rb][eb]);
                MFMA(ah[rb], bl[eb], a4[rb][eb]);
                MFMA(al[rb], bh[eb], a4[rb][eb]);
            }
            if (c < 4) wwrite(1024);
            __syncthreads();
        }
        // epilogue -> EFF[e][r] (overlays WA/BS, dead now)
#pragma unroll
        for (int rb = 0; rb < 2; ++rb){
            const int rel0 = wr*32 + rb*16 + lg*4;
            const int g = rel0 >> 3;
#pragma unroll
            for (int eb = 0; eb < 4; ++eb){
                const int e = wc*64 + eb*16 + lr;
                const int g2 = (g & ~3) | ((g & 3) ^ (e & 3));
                u16 h[4], l[4];
#pragma unroll
                for (int r = 0; r < 4; ++r){
                    const float v = fmaxf(a4[rb][eb][r], 0.f);
                    split2(v, h[r], l[r]);
                }
                const int ob = (e*10 + g2)*16 + (rel0 & 7)*2;
                *(u64*)(smem + EFF_H + ob) = pack4(h);
                *(u64*)(smem + EFF_L + ob) = pack4(l);
            }
        }
        // RRE staging -> [n][r] (overlays ACT, dead now)
        {
            const int n = t >> 1, half = t & 1;
#pragma unroll
            for (int gq = 0; gq < 4; ++gq){
                unsigned ph[4], pl[4];
#pragma unroll
                for (int i = 0; i < 4; ++i){
                    u16 h0, l0, h1, l1;
                    split2(vrr[gq*8 + 2*i],     h0, l0);
                    split2(vrr[gq*8 + 2*i + 1], h1, l1);
                    ph[i] = (unsigned)h0 | ((unsigned)h1 << 16);
                    pl[i] = (unsigned)l0 | ((unsigned)l1 << 16);
                }
                const int off = (n*10 + half*4 + (gq ^ (n & 3))) * 16;
                uint4v H; H[0]=ph[0]; H[1]=ph[1]; H[2]=ph[2]; H[3]=ph[3];
                uint4v L; L[0]=pl[0]; L[1]=pl[1]; L[2]=pl[2]; L[3]=pl[3];
                *(uint4v*)(smem + RRE_H + off) = H;
                *(uint4v*)(smem + RRE_L + off) = L;
            }
        }
        __syncthreads();
    }

    // ================= E: EF[n][e] += RR[n][r] * eff[r][e], [128 n x 128 e], K=64 =================
    {
        f32x4 ae[4][4];
#pragma unroll
        for (int nb = 0; nb < 4; ++nb)
#pragma unroll
        for (int eb = 0; eb < 4; ++eb){
            ae[nb][eb][0]=0.f; ae[nb][eb][1]=0.f; ae[nb][eb][2]=0.f; ae[nb][eb][3]=0.f;
        }
#pragma unroll
        for (int ks = 0; ks < 2; ++ks){
            bf16x8 rh[4], rl[4], eh[4], el[4];
#pragma unroll
            for (int nb = 0; nb < 4; ++nb){
                const int row = wr*64 + nb*16 + lr;
                const int off = (row*10 + ks*4 + (lg ^ (row & 3))) * 16;
                rh[nb] = RD(RRE_H + off); rl[nb] = RD(RRE_L + off);
            }
#pragma unroll
            for (int eb = 0; eb < 4; ++eb){
                const int row = wc*64 + eb*16 + lr;
                const int off = (row*10 + ks*4 + (lg ^ (row & 3))) * 16;
                eh[eb] = RD(EFF_H + off); el[eb] = RD(EFF_L + off);
            }
#pragma unroll
            for (int nb = 0; nb < 4; ++nb)
#pragma unroll
            for (int eb = 0; eb < 4; ++eb){
                MFMA(rh[nb], eh[eb], ae[nb][eb]);
                MFMA(rh[nb], el[eb], ae[nb][eb]);
                MFMA(rl[nb], eh[eb], ae[nb][eb]);
            }
        }
        float* EFb = EF + (size_t)b*N_*EFFD;
#pragma unroll
        for (int eb = 0; eb < 4; ++eb){
            const int e = wc*64 + eb*16 + lr;
            if (e < EFFD){
#pragma unroll
                for (int nb = 0; nb < 4; ++nb){
                    const int n0 = wr*64 + nb*16 + lg*4;
#pragma unroll
                    for (int r = 0; r < 4; ++r)
                        atomicAdd(&EFb[(size_t)(n0 + r)*EFFD + e], ae[nb][eb][r]);
                }
            }
        }
    }
}

// ---------------- k3: object MLP + sigmoid (unchanged) ----------------
__global__ __launch_bounds__(128) void k3_out(
    const float* __restrict__ EF, const float* __restrict__ obj,
    const float* __restrict__ ow1, const float* __restrict__ ob1,
    const float* __restrict__ ow2, const float* __restrict__ ob2,
    float* __restrict__ out) {
    __shared__ float y[OBJD + EFFD];
    __shared__ float red[128];
    const int bn = blockIdx.x;
    const int t  = threadIdx.x;
    if (t < OBJD) y[t] = obj[(size_t)bn * OBJD + t];
    if (t < EFFD) y[OBJD + t] = EF[(size_t)bn * EFFD + t];
    __syncthreads();
    float prod = 0.f;
    if (t < 100) {
        float h = ob1[t];
#pragma unroll
        for (int k = 0; k < OBJD + EFFD; ++k) h += y[k] * ow1[k * 100 + t];
        prod = fmaxf(h, 0.f) * ow2[t];
    }
    red[t] = prod;
    __syncthreads();
#pragma unroll
    for (int s = 64; s > 0; s >>= 1) {
        if (t < s) red[t] += red[t + s];
        __syncthreads();
    }
    if (t == 0) {
        const float x = red[0] + ob2[0];
        float sig;
        if (x >= 0.f) sig = 1.f / (1.f + expf(-x));
        else { const float e = expf(x); sig = e / (1.f + e); }
        out[bn] = sig;
    }
}

extern "C" void kernel_launch(void* const* d_in, const int* in_sizes, int n_in,
                              void* d_out, int out_size, void* d_ws, size_t ws_size,
                              hipStream_t stream) {
    const float* obj = (const float*)d_in[0];
    const float* SR  = (const float*)d_in[1];
    const float* RR  = (const float*)d_in[2];
    const float* REL = (const float*)d_in[3];
    const float* rw1 = (const float*)d_in[4];
    const float* rb1 = (const float*)d_in[5];
    const float* rw2 = (const float*)d_in[6];
    const float* rb2 = (const float*)d_in[7];
    const float* rw3 = (const float*)d_in[8];
    const float* rb3 = (const float*)d_in[9];
    const float* rw4 = (const float*)d_in[10];
    const float* rb4 = (const float*)d_in[11];
    const float* ow1 = (const float*)d_in[12];
    const float* ob1 = (const float*)d_in[13];
    const float* ow2 = (const float*)d_in[14];
    const float* ob2 = (const float*)d_in[15];
    float* out = (float*)d_out;
    float* ws  = (float*)d_ws;

    float* EF = ws;                               // [2048][100] fp32
    u16*   UA = (u16*)(ws + EF_FLOATS);           // bf16 hi/lo matrices

    hipMemsetAsync(EF, 0, (size_t)EF_FLOATS * sizeof(float), stream);

    k0a<<<dim3(160, B_), dim3(128), 0, stream>>>(obj, rw1, UA + U_A1H, UA + U_A1L);
    k0b<<<dim3(160, 3), dim3(160), 0, stream>>>(rw2, rw3, rw4,
                                                UA + U_W2H, UA + U_W2L,
                                                UA + U_W3H, UA + U_W3L,
                                                UA + U_W4H, UA + U_W4L);
    k1<<<dim3(NTILE, B_), dim3(256), 0, stream>>>(SR, RR, REL, rb1, rb2, rb3, rb4,
                                                  (const u16*)UA, EF);
    k3_out<<<dim3(B_ * N_), dim3(128), 0, stream>>>(EF, obj, ow1, ob1, ow2, ob2, out);
}

// Round 5
// 796.404 us; speedup vs baseline: 2.3472x; 1.0056x over previous
//
#include <hip/hip_runtime.h>
#include <math.h>

#define B_    16
#define N_    128
#define R_    16256
#define OBJD  64
#define RELD  32
#define EFFD  100
#define HID   150
#define MT    64             // relations per block
#define NTILE (R_ / MT)      // 254

typedef __bf16 bf16x8 __attribute__((ext_vector_type(8)));
typedef float  f32x4  __attribute__((ext_vector_type(4)));
typedef unsigned int  uint4v __attribute__((ext_vector_type(4)));
typedef unsigned short u16;
typedef unsigned long long u64;

#define MFMA(a,b,c) (c) = __builtin_amdgcn_mfma_f32_16x16x32_bf16((a), (b), (c), 0, 0, 0)

// granule-slot swizzles (slot = 16B unit within a 4-granule group)
// SWZA: for rows whose granule-count stride is == 4 (mod 8)   (WA 4/row, ACT 20/row)
// SWZE: for rows whose granule-count stride is == 2 (mod 8)   (RRE/EFF 10/row)
#define SWZA(r,g) ((g) ^ (((r) >> 1) & 3))
#define SWZE(r,g) ((g) ^ (((r) >> 2) & 3))

// ---------------- ws layout ----------------
#define EF_FLOATS (B_*N_*EFFD)       // 204800
#define A1_ELEMS  (B_*160*288)       // 737280
#define W2_ELEMS  (160*160)          // 25600
#define W4_ELEMS  (128*160)          // 20480
#define U_A1H 0
#define U_A1L (U_A1H + A1_ELEMS)
#define U_W2H (U_A1L + A1_ELEMS)
#define U_W2L (U_W2H + W2_ELEMS)
#define U_W3H (U_W2L + W2_ELEMS)
#define U_W3L (U_W3H + W2_ELEMS)
#define U_W4H (U_W3L + W2_ELEMS)
#define U_W4L (U_W4H + W4_ELEMS)

// ---- bf16 split helpers: x = hi + lo, both RNE bf16 ----
__device__ __forceinline__ u16 bfh(float x){
    unsigned u = __float_as_uint(x);
    return (u16)((u + 0x7FFFu + ((u >> 16) & 1u)) >> 16);
}
__device__ __forceinline__ float bff(u16 h){ return __uint_as_float(((unsigned)h) << 16); }
__device__ __forceinline__ void split2(float x, u16 &h, u16 &l){
    h = bfh(x);
    l = bfh(x - bff(h));
}
__device__ __forceinline__ u64 pack4(const u16 h[4]){
    return (u64)((unsigned)h[0] | ((unsigned)h[1] << 16))
         | ((u64)((unsigned)h[2] | ((unsigned)h[3] << 16)) << 32);
}

// ---------------- k0a: fold objects @ rw1 -> A1[b][out 160][k 288] hi/lo bf16 ----------------
__global__ __launch_bounds__(128) void k0a(const float* __restrict__ obj,
                                           const float* __restrict__ rw1,
                                           u16* __restrict__ A1H, u16* __restrict__ A1L){
    const int j = blockIdx.x;      // out 0..159 (>=150 -> zero rows)
    const int b = blockIdx.y;
    const int n = threadIdx.x;     // 0..127
    float s = 0.f, rc = 0.f;
    if (j < HID){
        const float* o = obj + ((size_t)b*N_ + n)*OBJD;
#pragma unroll
        for (int d = 0; d < OBJD; ++d){
            const float ov = o[d];
            s  += ov * rw1[d*HID + j];
            rc += ov * rw1[(OBJD + d)*HID + j];
        }
    }
    const size_t base = ((size_t)b*160 + j)*288;
    const int pos = (n & ~31) + (SWZA(j, (n >> 3) & 3) << 3) + (n & 7);
    u16 h, l;
    split2(s, h, l);  A1H[base + pos] = h;        A1L[base + pos] = l;
    split2(rc, h, l); A1H[base + 128 + pos] = h;  A1L[base + 128 + pos] = l;
    if (n < RELD){
        const float v = (j < HID) ? rw1[(2*OBJD + n)*HID + j] : 0.f;
        const int p2 = 256 + (SWZA(j, (n >> 3) & 3) << 3) + (n & 7);
        split2(v, h, l); A1H[base + p2] = h; A1L[base + p2] = l;
    }
}

// ---------------- k0b: transpose+split rw2/rw3/rw4 (swizzle pre-baked) ----------------
__global__ __launch_bounds__(160) void k0b(const float* __restrict__ rw2,
                                           const float* __restrict__ rw3,
                                           const float* __restrict__ rw4,
                                           u16* W2H, u16* W2L, u16* W3H, u16* W3L,
                                           u16* W4H, u16* W4L){
    const int out = blockIdx.x;    // 0..159
    const int m   = blockIdx.y;    // 0:rw2 1:rw3 2:rw4
    const int k   = threadIdx.x;   // 0..159
    const int pos = (k & ~31) + (SWZA(out, (k >> 3) & 3) << 3) + (k & 7);
    u16 h, l;
    if (m == 2){
        if (out >= 128) return;
        const float v = (out < EFFD && k < HID) ? rw4[k*EFFD + out] : 0.f;
        split2(v, h, l);
        W4H[out*160 + pos] = h; W4L[out*160 + pos] = l;
    } else {
        const float* W = (m == 0) ? rw2 : rw3;
        u16* DH = (m == 0) ? W2H : W3H;
        u16* DL = (m == 0) ? W2L : W3L;
        const float v = (out < HID && k < HID) ? W[k*HID + out] : 0.f;
        split2(v, h, l);
        DH[out*160 + pos] = h; DL[out*160 + pos] = l;
    }
}

// ---------------- k1: MFMA split-bf16 GEMM chain, double-buffered 1-barrier chunks ----------------
// LDS map (bytes):
// G1 loop : WAbuf[2] @ {0, 20480}          (each: H 10240 | L 10240)
//           BSbuf[2] @ {61440, 69632}      (each: H 4096  | L 4096)
// G2/G3   : ACT_H 0 | ACT_L 20480 ; WAbuf[2] @ {40960, 61440}
// G4      : ACT resident ; W4buf[2] @ {40960, 57344}   (each: H 8192 | L 8192)
// E       : RRE_H 0 | RRE_L 20480 | EFF_H 40960 | EFF_L 61440
#define G1WB(i) ((i) * 20480)
#define G1BS(i) (61440 + (i) * 8192)
#define ACT_H 0
#define ACT_L 20480
#define G2WB(i) (40960 + (i) * 20480)
#define G4WB(i) (40960 + (i) * 16384)
#define RRE_H 0
#define RRE_L 20480
#define EFF_H 40960
#define EFF_L 61440
#define SMEM_BYTES 81920

__global__ __launch_bounds__(256, 2) void k1(
    const float* __restrict__ SR, const float* __restrict__ RR, const float* __restrict__ REL,
    const float* __restrict__ rb1, const float* __restrict__ rb2,
    const float* __restrict__ rb3, const float* __restrict__ rb4,
    const u16* __restrict__ UA, float* __restrict__ EF){

    __shared__ __align__(16) unsigned char smem[SMEM_BYTES];

    const int t    = threadIdx.x;
    const int wid  = t >> 6;        // wave 0..3
    const int lane = t & 63;
    const int lr   = lane & 15;     // row/col within 16-block
    const int lg   = lane >> 4;     // k-granule 0..3
    const int wr   = wid >> 1;      // out/rel/n half
    const int wc   = wid & 1;       // rel/e half
    const int b    = blockIdx.y;
    const int r0   = blockIdx.x * MT;

    const u16* A1Hb = UA + U_A1H + (size_t)b*160*288;
    const u16* A1Lb = UA + U_A1L + (size_t)b*160*288;

    u64 wh[5], wl[5];     // weight chunk staging regs
    float bsv[8];         // G1 B staging regs

    auto wload = [&](const u16* GH, const u16* GL, int KW, int pieces, int c){
#pragma unroll
        for (int q = 0; q < 5; ++q){
            const int p = t + 256*q;
            if (p < pieces){
                const size_t off = (size_t)(p >> 3)*KW + c*32 + (p & 7)*4;
                wh[q] = *(const u64*)(GH + off);
                wl[q] = *(const u64*)(GL + off);
            }
        }
    };
    auto wwrite = [&](int base, int pieces){
        const int loff = pieces * 8;
#pragma unroll
        for (int q = 0; q < 5; ++q){
            const int p = t + 256*q;
            if (p < pieces){
                *(u64*)(smem + base + p*8)        = wh[q];
                *(u64*)(smem + base + loff + p*8) = wl[q];
            }
        }
    };
    // G1 B staging: SR/RR column-slices (register transpose), or REL rows
    auto bs_load_srr = [&](int c){  // chunk c: 0..3 SR, 4..7 RR
        const float* SRC = (c < 4) ? SR : RR;
        const float* base = SRC + ((size_t)b*N_ + (c & 3)*32 + wid*8)*R_ + r0 + lane;
#pragma unroll
        for (int q = 0; q < 8; ++q) bsv[q] = base[(size_t)q * R_];
    };
    auto bs_load_rel = [&](){
        const int rel = t >> 2, gq = t & 3;
        const float* src = REL + ((size_t)b*R_ + r0 + rel)*RELD + gq*8;
#pragma unroll
        for (int q = 0; q < 8; ++q) bsv[q] = src[q];
    };
    auto bs_pack_write = [&](int base, int rel, int gr){
        unsigned ph[4], pl[4];
#pragma unroll
        for (int i = 0; i < 4; ++i){
            u16 h0, l0, h1, l1;
            split2(bsv[2*i],   h0, l0);
            split2(bsv[2*i+1], h1, l1);
            ph[i] = (unsigned)h0 | ((unsigned)h1 << 16);
            pl[i] = (unsigned)l0 | ((unsigned)l1 << 16);
        }
        const int off = (rel*4 + SWZA(rel, gr)) * 16;
        uint4v H; H[0]=ph[0]; H[1]=ph[1]; H[2]=ph[2]; H[3]=ph[3];
        uint4v L; L[0]=pl[0]; L[1]=pl[1]; L[2]=pl[2]; L[3]=pl[3];
        *(uint4v*)(smem + base + off)        = H;
        *(uint4v*)(smem + base + 4096 + off) = L;
    };
    auto RD = [&](int off) -> bf16x8 {
        return __builtin_bit_cast(bf16x8, *(const uint4v*)(smem + off));
    };

    f32x4 acc[5][2];   // [out-block][rel-block], wave tile = 80 out x 32 rel

    auto epi_act = [&](){   // relu -> split -> ACT[rel][k=out]
#pragma unroll
        for (int mb = 0; mb < 5; ++mb){
            const int out0 = wr*80 + mb*16 + lg*4;
            const int g = out0 >> 3;
#pragma unroll
            for (int nb = 0; nb < 2; ++nb){
                const int rel = wc*32 + nb*16 + lr;
                const int g2 = (g & ~3) | SWZA(rel, g & 3);
                u16 h[4], l[4];
#pragma unroll
                for (int r = 0; r < 4; ++r){
                    const float v = fmaxf(acc[mb][nb][r], 0.f);
                    split2(v, h[r], l[r]);
                }
                const int ob = (rel*20 + g2)*16 + (out0 & 7)*2;
                *(u64*)(smem + ACT_H + ob) = pack4(h);
                *(u64*)(smem + ACT_L + ob) = pack4(l);
            }
        }
    };

    // ================= G1: [160 out x 64 rel], K = 288, double-buffered =================
    {
#pragma unroll
        for (int mb = 0; mb < 5; ++mb){
            const int o0 = wr*80 + mb*16 + lg*4;
            f32x4 bv;
#pragma unroll
            for (int r = 0; r < 4; ++r) bv[r] = (o0 + r < HID) ? rb1[o0 + r] : 0.f;
            acc[mb][0] = bv; acc[mb][1] = bv;
        }
        wload(A1Hb, A1Lb, 288, 1280, 0);
        bs_load_srr(0);
        wwrite(G1WB(0), 1280);
        bs_pack_write(G1BS(0), lane, wid);
        __syncthreads();
        for (int c = 0; c < 9; ++c){
            if (c < 8){
                wload(A1Hb, A1Lb, 288, 1280, c + 1);
                if (c + 1 < 8) bs_load_srr(c + 1); else bs_load_rel();
            }
            const int wb = G1WB(c & 1), bb = G1BS(c & 1);
            bf16x8 ah[5], al[5], bh[2], bl[2];
#pragma unroll
            for (int mb = 0; mb < 5; ++mb){
                const int row = wr*80 + mb*16 + lr;
                const int off = (row*4 + SWZA(row, lg)) * 16;
                ah[mb] = RD(wb + off); al[mb] = RD(wb + 10240 + off);
            }
#pragma unroll
            for (int nb = 0; nb < 2; ++nb){
                const int rel = wc*32 + nb*16 + lr;
                const int off = (rel*4 + SWZA(rel, lg)) * 16;
                bh[nb] = RD(bb + off); bl[nb] = RD(bb + 4096 + off);
            }
#pragma unroll
            for (int mb = 0; mb < 5; ++mb)
#pragma unroll
            for (int nb = 0; nb < 2; ++nb){
                MFMA(ah[mb], bh[nb], acc[mb][nb]);
                MFMA(ah[mb], bl[nb], acc[mb][nb]);
                MFMA(al[mb], bh[nb], acc[mb][nb]);
            }
            if (c < 8){
                wwrite(G1WB((c + 1) & 1), 1280);
                if (c + 1 < 8) bs_pack_write(G1BS((c + 1) & 1), lane, wid);
                else           bs_pack_write(G1BS((c + 1) & 1), t >> 2, t & 3);
            }
            __syncthreads();
        }
        epi_act();   // writes ACT over dead G1 WA buffers; next barrier is G2 prologue's
    }

    // ================= G2, G3: [160 x 64], K = 160 (B = ACT resident) =================
    {
        const u16* WHs[2] = { UA + U_W2H, UA + U_W3H };
        const u16* WLs[2] = { UA + U_W2L, UA + U_W3L };
        const float* RBs[2] = { rb2, rb3 };
        for (int L = 0; L < 2; ++L){
#pragma unroll
            for (int mb = 0; mb < 5; ++mb){
                const int o0 = wr*80 + mb*16 + lg*4;
                f32x4 bv;
#pragma unroll
                for (int r = 0; r < 4; ++r) bv[r] = (o0 + r < HID) ? RBs[L][o0 + r] : 0.f;
                acc[mb][0] = bv; acc[mb][1] = bv;
            }
            wload(WHs[L], WLs[L], 160, 1280, 0);
            wwrite(G2WB(0), 1280);
            __syncthreads();
            for (int c = 0; c < 5; ++c){
                if (c < 4) wload(WHs[L], WLs[L], 160, 1280, c + 1);
                const int wb = G2WB(c & 1);
                bf16x8 ah[5], al[5], bh[2], bl[2];
#pragma unroll
                for (int mb = 0; mb < 5; ++mb){
                    const int row = wr*80 + mb*16 + lr;
                    const int off = (row*4 + SWZA(row, lg)) * 16;
                    ah[mb] = RD(wb + off); al[mb] = RD(wb + 10240 + off);
                }
#pragma unroll
                for (int nb = 0; nb < 2; ++nb){
                    const int rel = wc*32 + nb*16 + lr;
                    const int off = (rel*20 + c*4 + SWZA(rel, lg)) * 16;
                    bh[nb] = RD(ACT_H + off); bl[nb] = RD(ACT_L + off);
                }
#pragma unroll
                for (int mb = 0; mb < 5; ++mb)
#pragma unroll
                for (int nb = 0; nb < 2; ++nb){
                    MFMA(ah[mb], bh[nb], acc[mb][nb]);
                    MFMA(ah[mb], bl[nb], acc[mb][nb]);
                    MFMA(al[mb], bh[nb], acc[mb][nb]);
                }
                if (c < 4) wwrite(G2WB((c + 1) & 1), 1280);
                __syncthreads();
            }
            epi_act();   // next barrier: following phase's prologue barrier
        }
    }

    // ================= G4: effects, flipped: [64 rel x 128 e], K = 160 =================
    {
        f32x4 a4[2][4];
#pragma unroll
        for (int eb = 0; eb < 4; ++eb){
            const int e = wc*64 + eb*16 + lr;
            const float bvv = (e < EFFD) ? rb4[e] : 0.f;
            f32x4 v; v[0]=bvv; v[1]=bvv; v[2]=bvv; v[3]=bvv;
            a4[0][eb] = v; a4[1][eb] = v;
        }
        // prefetch RR tile for E-phase staging (consumed after the loop)
        float vrr[32];
        {
            const int n = t >> 1, half = t & 1;
            const float* src = RR + ((size_t)b*N_ + n)*R_ + r0 + half*32;
#pragma unroll
            for (int q = 0; q < 8; ++q){
                const float4 f = *(const float4*)(src + q*4);
                vrr[q*4+0] = f.x; vrr[q*4+1] = f.y; vrr[q*4+2] = f.z; vrr[q*4+3] = f.w;
            }
        }
        const u16* W4Hp = UA + U_W4H;
        const u16* W4Lp = UA + U_W4L;
        wload(W4Hp, W4Lp, 160, 1024, 0);
        wwrite(G4WB(0), 1024);
        __syncthreads();
        for (int c = 0; c < 5; ++c){
            if (c < 4) wload(W4Hp, W4Lp, 160, 1024, c + 1);
            const int wb = G4WB(c & 1);
            bf16x8 ah[2], al[2], bh[4], bl[4];
#pragma unroll
            for (int rb = 0; rb < 2; ++rb){
                const int row = wr*32 + rb*16 + lr;
                const int off = (row*20 + c*4 + SWZA(row, lg)) * 16;
                ah[rb] = RD(ACT_H + off); al[rb] = RD(ACT_L + off);
            }
#pragma unroll
            for (int eb = 0; eb < 4; ++eb){
                const int row = wc*64 + eb*16 + lr;
                const int off = (row*4 + SWZA(row, lg)) * 16;
                bh[eb] = RD(wb + off); bl[eb] = RD(wb + 8192 + off);
            }
#pragma unroll
            for (int rb = 0; rb < 2; ++rb)
#pragma unroll
            for (int eb = 0; eb < 4; ++eb){
                MFMA(ah[rb], bh[eb], a4[rb][eb]);
                MFMA(ah[rb], bl[eb], a4[rb][eb]);
                MFMA(al[rb], bh[eb], a4[rb][eb]);
            }
            if (c < 4) wwrite(G4WB((c + 1) & 1), 1024);
            __syncthreads();
        }
        // epilogue -> EFF[e][r] (overlays G4 WA buffers, dead now)
#pragma unroll
        for (int rb = 0; rb < 2; ++rb){
            const int rel0 = wr*32 + rb*16 + lg*4;
            const int g = rel0 >> 3;
#pragma unroll
            for (int eb = 0; eb < 4; ++eb){
                const int e = wc*64 + eb*16 + lr;
                const int g2 = (g & ~3) | SWZE(e, g & 3);
                u16 h[4], l[4];
#pragma unroll
                for (int r = 0; r < 4; ++r){
                    const float v = fmaxf(a4[rb][eb][r], 0.f);
                    split2(v, h[r], l[r]);
                }
                const int ob = (e*10 + g2)*16 + (rel0 & 7)*2;
                *(u64*)(smem + EFF_H + ob) = pack4(h);
                *(u64*)(smem + EFF_L + ob) = pack4(l);
            }
        }
        // RRE staging -> [n][r] (overlays ACT, dead now)
        {
            const int n = t >> 1, half = t & 1;
#pragma unroll
            for (int gq = 0; gq < 4; ++gq){
                unsigned ph[4], pl[4];
#pragma unroll
                for (int i = 0; i < 4; ++i){
                    u16 h0, l0, h1, l1;
                    split2(vrr[gq*8 + 2*i],     h0, l0);
                    split2(vrr[gq*8 + 2*i + 1], h1, l1);
                    ph[i] = (unsigned)h0 | ((unsigned)h1 << 16);
                    pl[i] = (unsigned)l0 | ((unsigned)l1 << 16);
                }
                const int off = (n*10 + half*4 + SWZE(n, gq)) * 16;
                uint4v H; H[0]=ph[0]; H[1]=ph[1]; H[2]=ph[2]; H[3]=ph[3];
                uint4v L; L[0]=pl[0]; L[1]=pl[1]; L[2]=pl[2]; L[3]=pl[3];
                *(uint4v*)(smem + RRE_H + off) = H;
                *(uint4v*)(smem + RRE_L + off) = L;
            }
        }
        __syncthreads();
    }

    // ================= E: EF[n][e] += RR[n][r] * eff[r][e], [128 n x 128 e], K=64 =================
    {
        f32x4 ae[4][4];
#pragma unroll
        for (int nb = 0; nb < 4; ++nb)
#pragma unroll
        for (int eb = 0; eb < 4; ++eb){
            ae[nb][eb][0]=0.f; ae[nb][eb][1]=0.f; ae[nb][eb][2]=0.f; ae[nb][eb][3]=0.f;
        }
#pragma unroll
        for (int ks = 0; ks < 2; ++ks){
            bf16x8 rh[4], rl[4], eh[4], el[4];
#pragma unroll
            for (int nb = 0; nb < 4; ++nb){
                const int row = wr*64 + nb*16 + lr;
                const int off = (row*10 + ks*4 + SWZE(row, lg)) * 16;
                rh[nb] = RD(RRE_H + off); rl[nb] = RD(RRE_L + off);
            }
#pragma unroll
            for (int eb = 0; eb < 4; ++eb){
                const int row = wc*64 + eb*16 + lr;
                const int off = (row*10 + ks*4 + SWZE(row, lg)) * 16;
                eh[eb] = RD(EFF_H + off); el[eb] = RD(EFF_L + off);
            }
#pragma unroll
            for (int nb = 0; nb < 4; ++nb)
#pragma unroll
            for (int eb = 0; eb < 4; ++eb){
                MFMA(rh[nb], eh[eb], ae[nb][eb]);
                MFMA(rh[nb], el[eb], ae[nb][eb]);
                MFMA(rl[nb], eh[eb], ae[nb][eb]);
            }
        }
        float* EFb = EF + (size_t)b*N_*EFFD;
#pragma unroll
        for (int eb = 0; eb < 4; ++eb){
            const int e = wc*64 + eb*16 + lr;
            if (e < EFFD){
#pragma unroll
                for (int nb = 0; nb < 4; ++nb){
                    const int n0 = wr*64 + nb*16 + lg*4;
#pragma unroll
                    for (int r = 0; r < 4; ++r)
                        atomicAdd(&EFb[(size_t)(n0 + r)*EFFD + e], ae[nb][eb][r]);
                }
            }
        }
    }
}

// ---------------- k3: object MLP + sigmoid (unchanged) ----------------
__global__ __launch_bounds__(128) void k3_out(
    const float* __restrict__ EF, const float* __restrict__ obj,
    const float* __restrict__ ow1, const float* __restrict__ ob1,
    const float* __restrict__ ow2, const float* __restrict__ ob2,
    float* __restrict__ out) {
    __shared__ float y[OBJD + EFFD];
    __shared__ float red[128];
    const int bn = blockIdx.x;
    const int t  = threadIdx.x;
    if (t < OBJD) y[t] = obj[(size_t)bn * OBJD + t];
    if (t < EFFD) y[OBJD + t] = EF[(size_t)bn * EFFD + t];
    __syncthreads();
    float prod = 0.f;
    if (t < 100) {
        float h = ob1[t];
#pragma unroll
        for (int k = 0; k < OBJD + EFFD; ++k) h += y[k] * ow1[k * 100 + t];
        prod = fmaxf(h, 0.f) * ow2[t];
    }
    red[t] = prod;
    __syncthreads();
#pragma unroll
    for (int s = 64; s > 0; s >>= 1) {
        if (t < s) red[t] += red[t + s];
        __syncthreads();
    }
    if (t == 0) {
        const float x = red[0] + ob2[0];
        float sig;
        if (x >= 0.f) sig = 1.f / (1.f + expf(-x));
        else { const float e = expf(x); sig = e / (1.f + e); }
        out[bn] = sig;
    }
}

extern "C" void kernel_launch(void* const* d_in, const int* in_sizes, int n_in,
                              void* d_out, int out_size, void* d_ws, size_t ws_size,
                              hipStream_t stream) {
    const float* obj = (const float*)d_in[0];
    const float* SR  = (const float*)d_in[1];
    const float* RR  = (const float*)d_in[2];
    const float* REL = (const float*)d_in[3];
    const float* rw1 = (const float*)d_in[4];
    const float* rb1 = (const float*)d_in[5];
    const float* rw2 = (const float*)d_in[6];
    const float* rb2 = (const float*)d_in[7];
    const float* rw3 = (const float*)d_in[8];
    const float* rb3 = (const float*)d_in[9];
    const float* rw4 = (const float*)d_in[10];
    const float* rb4 = (const float*)d_in[11];
    const float* ow1 = (const float*)d_in[12];
    const float* ob1 = (const float*)d_in[13];
    const float* ow2 = (const float*)d_in[14];
    const float* ob2 = (const float*)d_in[15];
    float* out = (float*)d_out;
    float* ws  = (float*)d_ws;

    float* EF = ws;                               // [2048][100] fp32
    u16*   UA = (u16*)(ws + EF_FLOATS);           // bf16 hi/lo matrices

    hipMemsetAsync(EF, 0, (size_t)EF_FLOATS * sizeof(float), stream);

    k0a<<<dim3(160, B_), dim3(128), 0, stream>>>(obj, rw1, UA + U_A1H, UA + U_A1L);
    k0b<<<dim3(160, 3), dim3(160), 0, stream>>>(rw2, rw3, rw4,
                                                UA + U_W2H, UA + U_W2L,
                                                UA + U_W3H, UA + U_W3L,
                                                UA + U_W4H, UA + U_W4L);
    k1<<<dim3(NTILE, B_), dim3(256), 0, stream>>>(SR, RR, REL, rb1, rb2, rb3, rb4,
                                                  (const u16*)UA, EF);
    k3_out<<<dim3(B_ * N_), dim3(128), 0, stream>>>(EF, obj, ow1, ob1, ow2, ob2, out);
}